// Round 4
// baseline (489.372 us; speedup 1.0000x reference)
//
#include <hip/hip_runtime.h>
#include <math.h>

#define DIM   2048
#define NH    16
#define HD    128
#define BB    2
#define SS    2048
#define MTOT  4096   // BB*SS
#define NT    32     // DIM / 64 K-tiles

typedef unsigned short u16;
typedef short bf16x8 __attribute__((ext_vector_type(8)));
typedef float f32x4  __attribute__((ext_vector_type(4)));

typedef const void __attribute__((address_space(1)))* gas_ptr;
typedef void __attribute__((address_space(3)))* las_ptr;

__device__ __forceinline__ u16 f2bf(float f){
  union { float f; unsigned u; } v; v.f = f;
  unsigned r = v.u + 0x7FFFu + ((v.u >> 16) & 1u);
  return (u16)(r >> 16);
}
__device__ __forceinline__ float bf2f(u16 h){
  union { unsigned u; float f; } v; v.u = ((unsigned)h) << 16;
  return v.f;
}

// ---------------- fused fp32 -> bf16 conversion: x, Wq, Wk, Wv ----------------
__global__ __launch_bounds__(256) void cvt_all(
    const float* __restrict__ x,  const float* __restrict__ wq,
    const float* __restrict__ wk, const float* __restrict__ wv,
    u16* __restrict__ xb, u16* __restrict__ w0, u16* __restrict__ w1, u16* __restrict__ w2){
  int i = blockIdx.x * 256 + threadIdx.x;   // 0 .. 5242879 float4s
  const float* src; u16* dst; int j;
  if (i < 2097152) { src = x; dst = xb; j = i; }
  else {
    int k = i - 2097152;
    int seg = k >> 20;                      // 0..2
    j = k & 1048575;
    src = (seg == 0) ? wq : (seg == 1 ? wk : wv);
    dst = (seg == 0) ? w0 : (seg == 1 ? w1 : w2);
  }
  float4 v = ((const float4*)src)[j];
  ushort4 o;
  o.x = f2bf(v.x); o.y = f2bf(v.y); o.z = f2bf(v.z); o.w = f2bf(v.w);
  ((ushort4*)dst)[j] = o;
}

// ---------------- fp32 -> bf16 conversion (single tensor) ----------------
__global__ __launch_bounds__(256) void cvt_kernel(const float* __restrict__ in,
                                                  u16* __restrict__ out, int n4){
  int i = blockIdx.x * blockDim.x + threadIdx.x;
  if (i >= n4) return;
  float4 v = ((const float4*)in)[i];
  ushort4 o;
  o.x = f2bf(v.x); o.y = f2bf(v.y); o.z = f2bf(v.z); o.w = f2bf(v.w);
  ((ushort4*)out)[i] = o;
}

// ---------------- GEMM  C = A * B^T, 256x256 tile, BK=64, 8 waves, 8-phase ----------------
// Regions per K-tile: {A,B} x {k0,k1}, each 256x32 bf16 = 16KB, subtiled [r4][k4][16][8]
// so frag ds_read_b128 is a contiguous 1024B wave access (conflict-free) and
// global_load_lds' linear dest matches exactly. One region staged per phase into
// the other buffer; vmcnt(4) before the closing barrier of odd phases certifies
// regions 3-4 phases after issue, keeping 4 loads in flight (never vmcnt(0) mid-loop).
template<bool STORE_BF16>
__global__ __launch_bounds__(512, 2) void gemm256(
    const u16* __restrict__ A,
    const u16* __restrict__ B0, const u16* __restrict__ B1, const u16* __restrict__ B2,
    void* __restrict__ C0, void* __restrict__ C1, void* __restrict__ C2)
{
  __shared__ __align__(16) u16 Ar[2][2][256 * 32];   // [buf][kk] 16KB regions (64 KB)
  __shared__ __align__(16) u16 Br[2][2][256 * 32];   // (64 KB)

  const int tid  = threadIdx.x;
  const int lane = tid & 63;
  const int wave = tid >> 6;
  const int wm   = wave >> 2;          // 0..1  (M half)
  const int wn   = wave & 3;           // 0..3  (N quarter)
  const int lg   = lane >> 4;
  const int lr   = lane & 15;

  // bijective XCD-chunked swizzle (nwg % 8 == 0)
  const int cpx = gridDim.x >> 3;
  const int wg  = (blockIdx.x & 7) * cpx + (blockIdx.x >> 3);
  const int z   = wg >> 7;             // 128 tiles per z (16 m x 8 n)
  const int rem = wg & 127;
  const int m0  = (rem >> 3) * 256;
  const int n0  = (rem & 7) * 256;

  const u16* Bm = (z == 0) ? B0 : (z == 1 ? B1 : B2);
  void* Cm      = (z == 0) ? C0 : (z == 1 ? C1 : C2);
  const u16* Asrc = A  + (size_t)m0 * DIM;
  const u16* Bsrc = Bm + (size_t)n0 * DIM;

  f32x4 acc[8][4];
#pragma unroll
  for (int m = 0; m < 8; ++m)
#pragma unroll
    for (int n = 0; n < 4; ++n) acc[m][n] = (f32x4)0.0f;
  bf16x8 breg[4];

  // stage one 256x32 region (2 x global_load_lds width-16 per thread)
  auto stage = [&](const u16* src, u16* ldsreg, int kabs) {
#pragma unroll
    for (int it = 0; it < 2; ++it) {
      int c   = it * 512 + tid;
      int st  = c >> 4;
      int row = ((st >> 2) << 4) + (c & 15);
      int k   = kabs + ((st & 3) << 3);
      const u16* g = src + (size_t)row * DIM + k;
      char* l = (char*)ldsreg + (it * 512 + wave * 64) * 16;
      __builtin_amdgcn_global_load_lds((gas_ptr)g, (las_ptr)l, 16, 0, 0);
    }
  };

  // prologue: stage all 4 regions of tile 0 into buf 0
  stage(Asrc, Ar[0][0], 0);
  stage(Bsrc, Br[0][0], 0);
  stage(Asrc, Ar[0][1], 32);
  stage(Bsrc, Br[0][1], 32);
  asm volatile("s_waitcnt vmcnt(4)" ::: "memory");   // k0 regions landed; k1 in flight
  __builtin_amdgcn_s_barrier();

#define GPHASE(QQ, KK, GG)                                                              \
  {                                                                                     \
    const u16* Ab_ = Ar[b][KK];                                                         \
    const u16* Bb_ = Br[b][KK];                                                         \
    bf16x8 a0 = *(const bf16x8*)((const char*)Ab_ + ((((wm*8 + GG*4 + 0)*4 + lg) << 8) + (lr << 4))); \
    bf16x8 a1 = *(const bf16x8*)((const char*)Ab_ + ((((wm*8 + GG*4 + 1)*4 + lg) << 8) + (lr << 4))); \
    bf16x8 a2 = *(const bf16x8*)((const char*)Ab_ + ((((wm*8 + GG*4 + 2)*4 + lg) << 8) + (lr << 4))); \
    bf16x8 a3 = *(const bf16x8*)((const char*)Ab_ + ((((wm*8 + GG*4 + 3)*4 + lg) << 8) + (lr << 4))); \
    if (GG == 0) {                                                                      \
      _Pragma("unroll")                                                                 \
      for (int n_ = 0; n_ < 4; ++n_)                                                    \
        breg[n_] = *(const bf16x8*)((const char*)Bb_ + ((((wn*4 + n_)*4 + lg) << 8) + (lr << 4))); \
    }                                                                                   \
    if (t + 1 < NT) {                                                                   \
      if (QQ == 0) stage(Asrc, Ar[b ^ 1][0], (t + 1) * 64);                             \
      if (QQ == 1) stage(Bsrc, Br[b ^ 1][0], (t + 1) * 64);                             \
      if (QQ == 2) stage(Asrc, Ar[b ^ 1][1], (t + 1) * 64 + 32);                        \
      if (QQ == 3) stage(Bsrc, Br[b ^ 1][1], (t + 1) * 64 + 32);                        \
    }                                                                                   \
    __builtin_amdgcn_s_barrier();                                                       \
    asm volatile("s_waitcnt lgkmcnt(0)" ::: "memory");                                  \
    __builtin_amdgcn_sched_barrier(0);                                                  \
    __builtin_amdgcn_s_setprio(1);                                                      \
    {                                                                                   \
      acc[GG*4+0][0] = __builtin_amdgcn_mfma_f32_16x16x32_bf16(a0, breg[0], acc[GG*4+0][0], 0,0,0); \
      acc[GG*4+0][1] = __builtin_amdgcn_mfma_f32_16x16x32_bf16(a0, breg[1], acc[GG*4+0][1], 0,0,0); \
      acc[GG*4+0][2] = __builtin_amdgcn_mfma_f32_16x16x32_bf16(a0, breg[2], acc[GG*4+0][2], 0,0,0); \
      acc[GG*4+0][3] = __builtin_amdgcn_mfma_f32_16x16x32_bf16(a0, breg[3], acc[GG*4+0][3], 0,0,0); \
      acc[GG*4+1][0] = __builtin_amdgcn_mfma_f32_16x16x32_bf16(a1, breg[0], acc[GG*4+1][0], 0,0,0); \
      acc[GG*4+1][1] = __builtin_amdgcn_mfma_f32_16x16x32_bf16(a1, breg[1], acc[GG*4+1][1], 0,0,0); \
      acc[GG*4+1][2] = __builtin_amdgcn_mfma_f32_16x16x32_bf16(a1, breg[2], acc[GG*4+1][2], 0,0,0); \
      acc[GG*4+1][3] = __builtin_amdgcn_mfma_f32_16x16x32_bf16(a1, breg[3], acc[GG*4+1][3], 0,0,0); \
      acc[GG*4+2][0] = __builtin_amdgcn_mfma_f32_16x16x32_bf16(a2, breg[0], acc[GG*4+2][0], 0,0,0); \
      acc[GG*4+2][1] = __builtin_amdgcn_mfma_f32_16x16x32_bf16(a2, breg[1], acc[GG*4+2][1], 0,0,0); \
      acc[GG*4+2][2] = __builtin_amdgcn_mfma_f32_16x16x32_bf16(a2, breg[2], acc[GG*4+2][2], 0,0,0); \
      acc[GG*4+2][3] = __builtin_amdgcn_mfma_f32_16x16x32_bf16(a2, breg[3], acc[GG*4+2][3], 0,0,0); \
      acc[GG*4+3][0] = __builtin_amdgcn_mfma_f32_16x16x32_bf16(a3, breg[0], acc[GG*4+3][0], 0,0,0); \
      acc[GG*4+3][1] = __builtin_amdgcn_mfma_f32_16x16x32_bf16(a3, breg[1], acc[GG*4+3][1], 0,0,0); \
      acc[GG*4+3][2] = __builtin_amdgcn_mfma_f32_16x16x32_bf16(a3, breg[2], acc[GG*4+3][2], 0,0,0); \
      acc[GG*4+3][3] = __builtin_amdgcn_mfma_f32_16x16x32_bf16(a3, breg[3], acc[GG*4+3][3], 0,0,0); \
    }                                                                                   \
    __builtin_amdgcn_s_setprio(0);                                                      \
    if (QQ == 1) {                                                                      \
      if (t + 1 < NT) { asm volatile("s_waitcnt vmcnt(4)" ::: "memory"); }              \
      else            { asm volatile("s_waitcnt vmcnt(0)" ::: "memory"); }              \
    }                                                                                   \
    if (QQ == 3) {                                                                      \
      if (t + 1 < NT) { asm volatile("s_waitcnt vmcnt(4)" ::: "memory"); }              \
    }                                                                                   \
    __builtin_amdgcn_s_barrier();                                                       \
  }

  for (int t = 0; t < NT; ++t) {
    const int b = t & 1;
    GPHASE(0, 0, 0)
    GPHASE(1, 0, 1)
    GPHASE(2, 1, 0)
    GPHASE(3, 1, 1)
  }
#undef GPHASE

#pragma unroll
  for (int mf = 0; mf < 8; ++mf) {
    int grow = m0 + wm * 128 + mf * 16 + lg * 4;
#pragma unroll
    for (int nf = 0; nf < 4; ++nf) {
      int gcol = n0 + wn * 64 + nf * 16 + lr;
#pragma unroll
      for (int r = 0; r < 4; ++r) {
        float val = acc[mf][nf][r];
        if (STORE_BF16) ((u16*)Cm)[(size_t)(grow + r) * DIM + gcol]   = f2bf(val);
        else            ((float*)Cm)[(size_t)(grow + r) * DIM + gcol] = val;
      }
    }
  }
}

// ---------------- RoPE (in-place on Q and K, bf16) ----------------
__global__ __launch_bounds__(256) void rope_kernel(u16* __restrict__ Q, u16* __restrict__ Kt){
  int gid  = blockIdx.x * 4 + (threadIdx.x >> 6);
  int lane = threadIdx.x & 63;
  int h = gid & (NH - 1);
  int s = (gid >> 4) & (SS - 1);
  int b = gid >> 15;
  size_t base = ((size_t)(b * SS + s)) * DIM + (size_t)h * HD;

  float ang = (float)s * __expf(-(float)lane * 0.14391156831212787f);
  float c, sn;
  sincosf(ang, &sn, &c);
  int jh = lane >> 1;
  int par = lane & 1;

  unsigned pq = *(const unsigned*)(Q + base + 2 * lane);
  float qe = bf2f((u16)(pq & 0xffff)), qo = bf2f((u16)(pq >> 16));
  float qa  = __shfl(qe, jh),      qb  = __shfl(qo, jh);
  float qa2 = __shfl(qe, 32 + jh), qb2 = __shfl(qo, 32 + jh);
  float qxj   = par ? qb  : qa;
  float qxj64 = par ? qb2 : qa2;
  u16 q_lo = f2bf(qxj   * c - qo * sn);
  u16 q_hi = f2bf(qxj64 * c + qe * sn);

  unsigned pk = *(const unsigned*)(Kt + base + 2 * lane);
  float ke = bf2f((u16)(pk & 0xffff)), ko = bf2f((u16)(pk >> 16));
  float ka  = __shfl(ke, jh),      kb  = __shfl(ko, jh);
  float ka2 = __shfl(ke, 32 + jh), kb2 = __shfl(ko, 32 + jh);
  float kxj   = par ? kb  : ka;
  float kxj64 = par ? kb2 : ka2;
  u16 k_lo = f2bf(kxj   * c - ko * sn);
  u16 k_hi = f2bf(kxj64 * c + ke * sn);

  Q [base + lane] = q_lo;  Q [base + 64 + lane] = q_hi;
  Kt[base + lane] = k_lo;  Kt[base + 64 + lane] = k_hi;
}

// ---------------- V transpose: V[b,s,h,d] -> VT[bh][d][s] ----------------
__global__ __launch_bounds__(256) void transpose_v(const u16* __restrict__ V,
                                                   u16* __restrict__ VT){
  __shared__ __align__(16) u16 T[64 * 64];
  const int tid = threadIdx.x;
  const int s0 = blockIdx.x * 64;
  const int d0 = blockIdx.y * 64;
  const int bh = blockIdx.z;
  const int b = bh >> 4, h = bh & 15;

#pragma unroll
  for (int it = 0; it < 2; ++it) {
    int c = it * 256 + tid;          // 512 chunks of 8 elems
    int s = c >> 3, cc = c & 7;
    uint4 v = *(const uint4*)(V + (size_t)(b * SS + s0 + s) * DIM + h * HD + d0 + cc * 8);
    *(uint4*)((char*)T + s * 128 + (((cc ^ (s & 7)) & 7) << 4)) = v;
  }
  __syncthreads();
#pragma unroll
  for (int it = 0; it < 2; ++it) {
    int c = it * 256 + tid;
    int d = c >> 3, sc = c & 7;
    u16 tmp[8];
#pragma unroll
    for (int j = 0; j < 8; ++j) {
      int s = sc * 8 + j;
      tmp[j] = *(const u16*)((char*)T + s * 128 + ((((d >> 3) ^ (s & 7)) & 7) << 4) + (d & 7) * 2);
    }
    *(uint4*)(VT + (size_t)bh * HD * SS + (size_t)(d0 + d) * SS + s0 + sc * 8) = *(const uint4*)tmp;
  }
}

// ---------------- Flash attention (causal), QBLK=128, 8 waves, KV tile 64 ----------------
#define SCALE 0.08838834764831845f

__global__ __launch_bounds__(512) void attn_kernel(
    const u16* __restrict__ Q, const u16* __restrict__ Kg, const u16* __restrict__ VT,
    u16* __restrict__ AO)
{
  __shared__ __align__(16) u16 Klds[2][64 * 128];
  __shared__ __align__(16) u16 Vlds[2][128 * 64];
  __shared__ __align__(16) u16 Plds[8][16 * 64];

  const int tid  = threadIdx.x;
  const int lane = tid & 63;
  const int w    = tid >> 6;
  const int lg   = lane >> 4;
  const int lr   = lane & 15;
  const int pair = blockIdx.x;
  const int bh   = blockIdx.y;
  const int b    = bh >> 4, h = bh & 15;
  const size_t headoff = (size_t)b * SS * DIM + (size_t)h * HD;
  const u16* VTh = VT + (size_t)bh * HD * SS;

  for (int half = 0; half < 2; ++half) {
    const int Qt = half ? (15 - pair) : pair;
    const int qbase = Qt * 128;
    const int nkv = Qt * 2 + 2;

    bf16x8 qf[4];
    {
      const u16* qrow = Q + headoff + (size_t)(qbase + w * 16 + lr) * DIM;
#pragma unroll
      for (int kf = 0; kf < 4; ++kf)
        qf[kf] = *(const bf16x8*)(qrow + kf * 32 + lg * 8);
    }

    f32x4 o_acc[8];
#pragma unroll
    for (int nf = 0; nf < 8; ++nf) o_acc[nf] = (f32x4)0.0f;
    float mrow[4] = {-INFINITY, -INFINITY, -INFINITY, -INFINITY};
    float lrow[4] = {0.f, 0.f, 0.f, 0.f};

    int cur = 0;

#define STAGE(BUF, T)                                                              \
    {                                                                              \
      const int kv0s = (T) * 64;                                                   \
      _Pragma("unroll")                                                            \
      for (int it = 0; it < 2; ++it) {                                             \
        int c = it * 512 + tid;                                                    \
        int r = c >> 4, slot = c & 15;                                             \
        int cc = slot ^ (r & 7);                                                   \
        const u16* ga = Kg + headoff + (size_t)(kv0s + r) * DIM + cc * 8;          \
        char* la = (char*)Klds[BUF] + (it * 512 + w * 64) * 16;                    \
        __builtin_amdgcn_global_load_lds((gas_ptr)ga, (las_ptr)la, 16, 0, 0);      \
      }                                                                            \
      _Pragma("unroll")                                                            \
      for (int it = 0; it < 2; ++it) {                                             \
        int c = it * 512 + tid;                                                    \
        int d = c >> 3, slot = c & 7;                                              \
        int cc = slot ^ (d & 7);                                                   \
        const u16* gv = VTh + (size_t)d * SS + kv0s + cc * 8;                      \
        char* lv = (char*)Vlds[BUF] + (it * 512 + w * 64) * 16;                    \
        __builtin_amdgcn_global_load_lds((gas_ptr)gv, (las_ptr)lv, 16, 0, 0);      \
      }                                                                            \
    }

    STAGE(0, 0);
    __syncthreads();

    for (int t = 0; t < nkv; ++t) {
      const int kv0 = t * 64;
      if (t + 1 < nkv) STAGE(cur ^ 1, t + 1);

      if (kv0 <= qbase + w * 16 + 15) {
        f32x4 sacc[4];
#pragma unroll
        for (int sf = 0; sf < 4; ++sf) {
          sacc[sf] = (f32x4)0.0f;
          int row = sf * 16 + lr;
          int sw = row & 7;
#pragma unroll
          for (int kf = 0; kf < 4; ++kf) {
            int cc = kf * 4 + lg;
            bf16x8 kfrag = *(const bf16x8*)((char*)Klds[cur] + row * 256 + ((cc ^ sw) << 4));
            sacc[sf] = __builtin_amdgcn_mfma_f32_16x16x32_bf16(qf[kf], kfrag, sacc[sf], 0, 0, 0);
          }
        }

        float p[4][4];
        float mt[4];
#pragma unroll
        for (int r = 0; r < 4; ++r) {
          int qrow = qbase + w * 16 + lg * 4 + r;
          float mx = -INFINITY;
#pragma unroll
          for (int sf = 0; sf < 4; ++sf) {
            float v = sacc[sf][r] * SCALE;
            if (kv0 + sf * 16 + lr > qrow) v = -INFINITY;
            p[sf][r] = v;
            mx = fmaxf(mx, v);
          }
          mx = fmaxf(mx, __shfl_xor(mx, 1));
          mx = fmaxf(mx, __shfl_xor(mx, 2));
          mx = fmaxf(mx, __shfl_xor(mx, 4));
          mx = fmaxf(mx, __shfl_xor(mx, 8));
          mt[r] = mx;
        }
        float alpha[4];
#pragma unroll
        for (int r = 0; r < 4; ++r) {
          float mn = fmaxf(mrow[r], mt[r]);
          alpha[r] = __expf(mrow[r] - mn);
          mrow[r] = mn;
        }
#pragma unroll
        for (int r = 0; r < 4; ++r) {
          float s = 0.f;
#pragma unroll
          for (int sf = 0; sf < 4; ++sf) {
            float pv = __expf(p[sf][r] - mrow[r]);
            p[sf][r] = pv;
            s += pv;
          }
          s += __shfl_xor(s, 1);
          s += __shfl_xor(s, 2);
          s += __shfl_xor(s, 4);
          s += __shfl_xor(s, 8);
          lrow[r] = lrow[r] * alpha[r] + s;
        }
#pragma unroll
        for (int nf = 0; nf < 8; ++nf)
#pragma unroll
          for (int r = 0; r < 4; ++r) o_acc[nf][r] *= alpha[r];

#pragma unroll
        for (int sf = 0; sf < 4; ++sf)
#pragma unroll
          for (int r = 0; r < 4; ++r) {
            int row = lg * 4 + r, col = sf * 16 + lr;
            int byteoff = (row * 128 + col * 2) ^ ((row & 7) << 4);
            *(u16*)((char*)Plds[w] + byteoff) = f2bf(p[sf][r]);
          }

#pragma unroll
        for (int ks = 0; ks < 2; ++ks) {
          bf16x8 pfrag = *(const bf16x8*)((char*)Plds[w] + ((lr * 128 + ks * 64 + lg * 16) ^ ((lr & 7) << 4)));
#pragma unroll
          for (int nf = 0; nf < 8; ++nf) {
            int vrow = nf * 16 + lr;
            int cc = ks * 4 + lg;
            bf16x8 vfrag = *(const bf16x8*)((char*)Vlds[cur] + vrow * 128 + ((cc ^ (vrow & 7)) << 4));
            o_acc[nf] = __builtin_amdgcn_mfma_f32_16x16x32_bf16(pfrag, vfrag, o_acc[nf], 0, 0, 0);
          }
        }
      }

      __syncthreads();
      cur ^= 1;
    }

    float inv[4];
#pragma unroll
    for (int r = 0; r < 4; ++r) inv[r] = 1.0f / lrow[r];
#pragma unroll
    for (int nf = 0; nf < 8; ++nf)
#pragma unroll
      for (int r = 0; r < 4; ++r) {
        int grow = qbase + w * 16 + lg * 4 + r;
        int col  = nf * 16 + lr;
        AO[(size_t)(b * SS + grow) * DIM + h * HD + col] = f2bf(o_acc[nf][r] * inv[r]);
      }
#undef STAGE
  }
}

// ---------------- launch ----------------
extern "C" void kernel_launch(void* const* d_in, const int* in_sizes, int n_in,
                              void* d_out, int out_size, void* d_ws, size_t ws_size,
                              hipStream_t stream)
{
  const float* x  = (const float*)d_in[0];
  const float* Wq = (const float*)d_in[1];
  const float* Wk = (const float*)d_in[2];
  const float* Wv = (const float*)d_in[3];
  const float* Wo = (const float*)d_in[4];
  float* out = (float*)d_out;

  char* ws = (char*)d_ws;
  const size_t XB_BYTES = (size_t)MTOT * DIM * 2;   // 16 MB
  const size_t W_BYTES  = (size_t)DIM * DIM * 2;    // 8 MB
  u16* xb = (u16*)ws;                                // x bf16; later reused as AO
  u16* w0 = (u16*)(ws + XB_BYTES);                   // Wq, later Wo
  u16* w1 = (u16*)(ws + XB_BYTES + W_BYTES);         // Wk, later VT (spans w1+w2)
  u16* w2 = (u16*)(ws + XB_BYTES + 2 * W_BYTES);     // Wv
  u16* Qb = (u16*)(ws + XB_BYTES + 3 * W_BYTES);
  u16* Kb = Qb + (size_t)MTOT * DIM;
  u16* Vb = Kb + (size_t)MTOT * DIM;
  u16* AO = xb;
  u16* VTb = w1;                                     // 16 MB (w1+w2), free after QKV GEMM

  cvt_all<<<20480, 256, 0, stream>>>(x, Wq, Wk, Wv, xb, w0, w1, w2);

  gemm256<true><<<dim3(384), 512, 0, stream>>>(xb, w0, w1, w2,
                                               (void*)Qb, (void*)Kb, (void*)Vb);

  transpose_v<<<dim3(32, 2, 32), 256, 0, stream>>>(Vb, VTb);

  rope_kernel<<<16384, 256, 0, stream>>>(Qb, Kb);

  cvt_kernel<<<4096, 256, 0, stream>>>(Wo, w0, 1048576);  // Wq slot no longer needed

  attn_kernel<<<dim3(8, 32), 512, 0, stream>>>(Qb, Kb, VTb, AO);

  gemm256<false><<<dim3(128), 512, 0, stream>>>(AO, w0, w0, w0,
                                                (void*)out, (void*)out, (void*)out);
}

// Round 7
// 470.647 us; speedup vs baseline: 1.0398x; 1.0398x over previous
//
#include <hip/hip_runtime.h>
#include <math.h>

#define DIM   2048
#define NH    16
#define HD    128
#define BB    2
#define SS    2048
#define MTOT  4096   // BB*SS
#define NTK   64     // DIM / 32 K-tiles

typedef unsigned short u16;
typedef short bf16x8 __attribute__((ext_vector_type(8)));
typedef float f32x4  __attribute__((ext_vector_type(4)));

typedef const void __attribute__((address_space(1)))* gas_ptr;
typedef void __attribute__((address_space(3)))* las_ptr;

__device__ __forceinline__ u16 f2bf(float f){
  union { float f; unsigned u; } v; v.f = f;
  unsigned r = v.u + 0x7FFFu + ((v.u >> 16) & 1u);
  return (u16)(r >> 16);
}
__device__ __forceinline__ float bf2f(u16 h){
  union { unsigned u; float f; } v; v.u = ((unsigned)h) << 16;
  return v.f;
}

// ---------------- fused fp32 -> bf16 conversion: x, Wq, Wk, Wv ----------------
__global__ __launch_bounds__(256) void cvt_all(
    const float* __restrict__ x,  const float* __restrict__ wq,
    const float* __restrict__ wk, const float* __restrict__ wv,
    u16* __restrict__ xb, u16* __restrict__ w0, u16* __restrict__ w1, u16* __restrict__ w2){
  int i = blockIdx.x * 256 + threadIdx.x;   // 0 .. 5242879 float4s
  const float* src; u16* dst; int j;
  if (i < 2097152) { src = x; dst = xb; j = i; }
  else {
    int k = i - 2097152;
    int seg = k >> 20;                      // 0..2
    j = k & 1048575;
    src = (seg == 0) ? wq : (seg == 1 ? wk : wv);
    dst = (seg == 0) ? w0 : (seg == 1 ? w1 : w2);
  }
  float4 v = ((const float4*)src)[j];
  ushort4 o;
  o.x = f2bf(v.x); o.y = f2bf(v.y); o.z = f2bf(v.z); o.w = f2bf(v.w);
  ((ushort4*)dst)[j] = o;
}

// ---------------- fp32 -> bf16 conversion (single tensor) ----------------
__global__ __launch_bounds__(256) void cvt_kernel(const float* __restrict__ in,
                                                  u16* __restrict__ out, int n4){
  int i = blockIdx.x * blockDim.x + threadIdx.x;
  if (i >= n4) return;
  float4 v = ((const float4*)in)[i];
  ushort4 o;
  o.x = f2bf(v.x); o.y = f2bf(v.y); o.z = f2bf(v.z); o.w = f2bf(v.w);
  ((ushort4*)out)[i] = o;
}

// ---------------- GEMM  C = A * B^T, 256x256 tile, BK=32, 8 waves, deep pipeline ----------------
// 4 tile-buffers; stage distance 3 tiles (half h of tile t+3 staged at phase h of
// tile t); reads touch buf t&3 only -> stages never write a buffer being read.
// One counted vmcnt(8) per tile certifies tile t+1 with tiles t+2,t+3 (8 loads)
// still in flight (~4-6 phases issue->certify slack). LDS halves are [m16][k8][16][8]
// subtiled: frag ds_read_b128 is a contiguous 1024B wave access (conflict-free)
// and matches global_load_lds' linear lane order exactly.
template<bool STORE_BF16>
__global__ __launch_bounds__(512, 2) void gemm256(
    const u16* __restrict__ A,
    const u16* __restrict__ B0, const u16* __restrict__ B1, const u16* __restrict__ B2,
    void* __restrict__ C0, void* __restrict__ C1, void* __restrict__ C2)
{
  __shared__ __align__(16) u16 Abuf[4][2][4096];   // [buf][half 128 rows][8KB]
  __shared__ __align__(16) u16 Bbuf[4][2][4096];

  const int tid  = threadIdx.x;
  const int lane = tid & 63;
  const int wave = tid >> 6;
  const int wm   = wave >> 2;          // 0..1  (M half)
  const int wn   = wave & 3;           // 0..3  (N quarter)
  const int lg   = lane >> 4;
  const int lr   = lane & 15;

  // bijective XCD-chunked swizzle (nwg % 8 == 0)
  const int cpx = gridDim.x >> 3;
  const int wg  = (blockIdx.x & 7) * cpx + (blockIdx.x >> 3);
  const int z   = wg >> 7;             // 128 tiles per z (16 m x 8 n)
  const int rem = wg & 127;
  const int m0  = (rem >> 3) * 256;
  const int n0  = (rem & 7) * 256;

  const u16* Bm = (z == 0) ? B0 : (z == 1 ? B1 : B2);
  void* Cm      = (z == 0) ? C0 : (z == 1 ? C1 : C2);
  const u16* Asrc = A  + (size_t)m0 * DIM;
  const u16* Bsrc = Bm + (size_t)n0 * DIM;

  f32x4 acc[8][4];
#pragma unroll
  for (int m = 0; m < 8; ++m)
#pragma unroll
    for (int n = 0; n < 4; ++n) acc[m][n] = (f32x4)0.0f;
  bf16x8 breg[4];

  // stage one 128x32 half (1 x global_load_lds width-16 per thread)
  auto stageHalf = [&](const u16* src, int rowbase, int kt, u16* lds) {
    int s   = tid >> 4;                 // 0..31 subtile
    int m16 = s >> 2, k8 = s & 3;
    int row = rowbase + m16 * 16 + (tid & 15);
    const u16* g = src + (size_t)row * DIM + kt * 32 + k8 * 8;
    char* l = (char*)lds + wave * 1024 + lane * 16;   // wave-uniform base + lane*16
    __builtin_amdgcn_global_load_lds((gas_ptr)g, (las_ptr)l, 16, 0, 0);
  };

  // prologue: stage tiles 0..2 fully (12 loads); certify tile 0, keep 1,2 in flight
#pragma unroll
  for (int pt = 0; pt < 3; ++pt) {
    stageHalf(Asrc, 0,   pt, Abuf[pt][0]);
    stageHalf(Bsrc, 0,   pt, Bbuf[pt][0]);
    stageHalf(Asrc, 128, pt, Abuf[pt][1]);
    stageHalf(Bsrc, 128, pt, Bbuf[pt][1]);
  }
  asm volatile("s_waitcnt vmcnt(8)" ::: "memory");
  __builtin_amdgcn_s_barrier();

#define PH(Q)                                                                           \
  {                                                                                     \
    bf16x8 a_[4];                                                                       \
    _Pragma("unroll")                                                                   \
    for (int m = 0; m < 4; ++m)                                                         \
      a_[m] = *(const bf16x8*)((const char*)Ah + ((((Q*4 + m)*4 + lg) << 8) + (lr << 4))); \
    if (Q == 0) {                                                                       \
      _Pragma("unroll")                                                                 \
      for (int nf = 0; nf < 4; ++nf)                                                    \
        breg[nf] = *(const bf16x8*)((const char*)Bh + (((((wn & 1)*4 + nf)*4 + lg) << 8) + (lr << 4))); \
    }                                                                                   \
    if (doStage) {                                                                      \
      stageHalf(Asrc, Q * 128, t + 3, Abuf[sb][Q]);                                     \
      stageHalf(Bsrc, Q * 128, t + 3, Bbuf[sb][Q]);                                     \
    }                                                                                   \
    __builtin_amdgcn_s_barrier();                                                       \
    asm volatile("s_waitcnt lgkmcnt(0)" ::: "memory");                                  \
    __builtin_amdgcn_sched_barrier(0);                                                  \
    __builtin_amdgcn_s_setprio(1);                                                      \
    _Pragma("unroll")                                                                   \
    for (int m = 0; m < 4; ++m)                                                         \
      _Pragma("unroll")                                                                 \
      for (int nf = 0; nf < 4; ++nf)                                                    \
        acc[Q*4 + m][nf] = __builtin_amdgcn_mfma_f32_16x16x32_bf16(a_[m], breg[nf], acc[Q*4 + m][nf], 0, 0, 0); \
    __builtin_amdgcn_s_setprio(0);                                                      \
  }

  for (int t = 0; t < NTK; ++t) {
    const int buf = t & 3;
    const int sb  = (t + 3) & 3;
    const bool doStage = (t + 3) < NTK;
    const u16* Ah = Abuf[buf][wm];
    const u16* Bh = Bbuf[buf][wn >> 1];

    PH(0)
    __builtin_amdgcn_s_barrier();

    PH(1)
    if (t < NTK - 3)       { asm volatile("s_waitcnt vmcnt(8)" ::: "memory"); }
    else if (t == NTK - 3) { asm volatile("s_waitcnt vmcnt(4)" ::: "memory"); }
    else if (t == NTK - 2) { asm volatile("s_waitcnt vmcnt(0)" ::: "memory"); }
    __builtin_amdgcn_s_barrier();
  }
#undef PH

#pragma unroll
  for (int mf = 0; mf < 8; ++mf) {
    int grow = m0 + wm * 128 + mf * 16 + lg * 4;
#pragma unroll
    for (int nf = 0; nf < 4; ++nf) {
      int gcol = n0 + wn * 64 + nf * 16 + lr;
#pragma unroll
      for (int r = 0; r < 4; ++r) {
        float val = acc[mf][nf][r];
        if (STORE_BF16) ((u16*)Cm)[(size_t)(grow + r) * DIM + gcol]   = f2bf(val);
        else            ((float*)Cm)[(size_t)(grow + r) * DIM + gcol] = val;
      }
    }
  }
}

// ---------------- RoPE (in-place on Q and K, bf16) ----------------
__global__ __launch_bounds__(256) void rope_kernel(u16* __restrict__ Q, u16* __restrict__ Kt){
  int gid  = blockIdx.x * 4 + (threadIdx.x >> 6);
  int lane = threadIdx.x & 63;
  int h = gid & (NH - 1);
  int s = (gid >> 4) & (SS - 1);
  int b = gid >> 15;
  size_t base = ((size_t)(b * SS + s)) * DIM + (size_t)h * HD;

  float ang = (float)s * __expf(-(float)lane * 0.14391156831212787f);
  float c, sn;
  sincosf(ang, &sn, &c);
  int jh = lane >> 1;
  int par = lane & 1;

  unsigned pq = *(const unsigned*)(Q + base + 2 * lane);
  float qe = bf2f((u16)(pq & 0xffff)), qo = bf2f((u16)(pq >> 16));
  float qa  = __shfl(qe, jh),      qb  = __shfl(qo, jh);
  float qa2 = __shfl(qe, 32 + jh), qb2 = __shfl(qo, 32 + jh);
  float qxj   = par ? qb  : qa;
  float qxj64 = par ? qb2 : qa2;
  u16 q_lo = f2bf(qxj   * c - qo * sn);
  u16 q_hi = f2bf(qxj64 * c + qe * sn);

  unsigned pk = *(const unsigned*)(Kt + base + 2 * lane);
  float ke = bf2f((u16)(pk & 0xffff)), ko = bf2f((u16)(pk >> 16));
  float ka  = __shfl(ke, jh),      kb  = __shfl(ko, jh);
  float ka2 = __shfl(ke, 32 + jh), kb2 = __shfl(ko, 32 + jh);
  float kxj   = par ? kb  : ka;
  float kxj64 = par ? kb2 : ka2;
  u16 k_lo = f2bf(kxj   * c - ko * sn);
  u16 k_hi = f2bf(kxj64 * c + ke * sn);

  Q [base + lane] = q_lo;  Q [base + 64 + lane] = q_hi;
  Kt[base + lane] = k_lo;  Kt[base + 64 + lane] = k_hi;
}

// ---------------- V transpose: V[b,s,h,d] -> VT[bh][d][s] ----------------
__global__ __launch_bounds__(256) void transpose_v(const u16* __restrict__ V,
                                                   u16* __restrict__ VT){
  __shared__ __align__(16) u16 T[64 * 64];
  const int tid = threadIdx.x;
  const int s0 = blockIdx.x * 64;
  const int d0 = blockIdx.y * 64;
  const int bh = blockIdx.z;
  const int b = bh >> 4, h = bh & 15;

#pragma unroll
  for (int it = 0; it < 2; ++it) {
    int c = it * 256 + tid;          // 512 chunks of 8 elems
    int s = c >> 3, cc = c & 7;
    uint4 v = *(const uint4*)(V + (size_t)(b * SS + s0 + s) * DIM + h * HD + d0 + cc * 8);
    *(uint4*)((char*)T + s * 128 + (((cc ^ (s & 7)) & 7) << 4)) = v;
  }
  __syncthreads();
#pragma unroll
  for (int it = 0; it < 2; ++it) {
    int c = it * 256 + tid;
    int d = c >> 3, sc = c & 7;
    u16 tmp[8];
#pragma unroll
    for (int j = 0; j < 8; ++j) {
      int s = sc * 8 + j;
      tmp[j] = *(const u16*)((char*)T + s * 128 + ((((d >> 3) ^ (s & 7)) & 7) << 4) + (d & 7) * 2);
    }
    *(uint4*)(VT + (size_t)bh * HD * SS + (size_t)(d0 + d) * SS + s0 + sc * 8) = *(const uint4*)tmp;
  }
}

// ---------------- Flash attention (causal), QBLK=128, 8 waves, KV tile 64 ----------------
#define SCALE 0.08838834764831845f

__global__ __launch_bounds__(512) void attn_kernel(
    const u16* __restrict__ Q, const u16* __restrict__ Kg, const u16* __restrict__ VT,
    u16* __restrict__ AO)
{
  __shared__ __align__(16) u16 Klds[2][64 * 128];
  __shared__ __align__(16) u16 Vlds[2][128 * 64];
  __shared__ __align__(16) u16 Plds[8][16 * 64];

  const int tid  = threadIdx.x;
  const int lane = tid & 63;
  const int w    = tid >> 6;
  const int lg   = lane >> 4;
  const int lr   = lane & 15;
  const int pair = blockIdx.x;
  const int bh   = blockIdx.y;
  const int b    = bh >> 4, h = bh & 15;
  const size_t headoff = (size_t)b * SS * DIM + (size_t)h * HD;
  const u16* VTh = VT + (size_t)bh * HD * SS;

  for (int half = 0; half < 2; ++half) {
    const int Qt = half ? (15 - pair) : pair;
    const int qbase = Qt * 128;
    const int nkv = Qt * 2 + 2;

    bf16x8 qf[4];
    {
      const u16* qrow = Q + headoff + (size_t)(qbase + w * 16 + lr) * DIM;
#pragma unroll
      for (int kf = 0; kf < 4; ++kf)
        qf[kf] = *(const bf16x8*)(qrow + kf * 32 + lg * 8);
    }

    f32x4 o_acc[8];
#pragma unroll
    for (int nf = 0; nf < 8; ++nf) o_acc[nf] = (f32x4)0.0f;
    float mrow[4] = {-INFINITY, -INFINITY, -INFINITY, -INFINITY};
    float lrow[4] = {0.f, 0.f, 0.f, 0.f};

    int cur = 0;

#define STAGE(BUF, T)                                                              \
    {                                                                              \
      const int kv0s = (T) * 64;                                                   \
      _Pragma("unroll")                                                            \
      for (int it = 0; it < 2; ++it) {                                             \
        int c = it * 512 + tid;                                                    \
        int r = c >> 4, slot = c & 15;                                             \
        int cc = slot ^ (r & 7);                                                   \
        const u16* ga = Kg + headoff + (size_t)(kv0s + r) * DIM + cc * 8;          \
        char* la = (char*)Klds[BUF] + (it * 512 + w * 64) * 16;                    \
        __builtin_amdgcn_global_load_lds((gas_ptr)ga, (las_ptr)la, 16, 0, 0);      \
      }                                                                            \
      _Pragma("unroll")                                                            \
      for (int it = 0; it < 2; ++it) {                                             \
        int c = it * 512 + tid;                                                    \
        int d = c >> 3, slot = c & 7;                                              \
        int cc = slot ^ (d & 7);                                                   \
        const u16* gv = VTh + (size_t)d * SS + kv0s + cc * 8;                      \
        char* lv = (char*)Vlds[BUF] + (it * 512 + w * 64) * 16;                    \
        __builtin_amdgcn_global_load_lds((gas_ptr)gv, (las_ptr)lv, 16, 0, 0);      \
      }                                                                            \
    }

    STAGE(0, 0);
    __syncthreads();

    for (int t = 0; t < nkv; ++t) {
      const int kv0 = t * 64;
      if (t + 1 < nkv) STAGE(cur ^ 1, t + 1);

      if (kv0 <= qbase + w * 16 + 15) {
        f32x4 sacc[4];
#pragma unroll
        for (int sf = 0; sf < 4; ++sf) {
          sacc[sf] = (f32x4)0.0f;
          int row = sf * 16 + lr;
          int sw = row & 7;
#pragma unroll
          for (int kf = 0; kf < 4; ++kf) {
            int cc = kf * 4 + lg;
            bf16x8 kfrag = *(const bf16x8*)((char*)Klds[cur] + row * 256 + ((cc ^ sw) << 4));
            sacc[sf] = __builtin_amdgcn_mfma_f32_16x16x32_bf16(qf[kf], kfrag, sacc[sf], 0, 0, 0);
          }
        }

        float p[4][4];
        float mt[4];
#pragma unroll
        for (int r = 0; r < 4; ++r) {
          int qrow = qbase + w * 16 + lg * 4 + r;
          float mx = -INFINITY;
#pragma unroll
          for (int sf = 0; sf < 4; ++sf) {
            float v = sacc[sf][r] * SCALE;
            if (kv0 + sf * 16 + lr > qrow) v = -INFINITY;
            p[sf][r] = v;
            mx = fmaxf(mx, v);
          }
          mx = fmaxf(mx, __shfl_xor(mx, 1));
          mx = fmaxf(mx, __shfl_xor(mx, 2));
          mx = fmaxf(mx, __shfl_xor(mx, 4));
          mx = fmaxf(mx, __shfl_xor(mx, 8));
          mt[r] = mx;
        }
        float alpha[4];
#pragma unroll
        for (int r = 0; r < 4; ++r) {
          float mn = fmaxf(mrow[r], mt[r]);
          alpha[r] = __expf(mrow[r] - mn);
          mrow[r] = mn;
        }
#pragma unroll
        for (int r = 0; r < 4; ++r) {
          float s = 0.f;
#pragma unroll
          for (int sf = 0; sf < 4; ++sf) {
            float pv = __expf(p[sf][r] - mrow[r]);
            p[sf][r] = pv;
            s += pv;
          }
          s += __shfl_xor(s, 1);
          s += __shfl_xor(s, 2);
          s += __shfl_xor(s, 4);
          s += __shfl_xor(s, 8);
          lrow[r] = lrow[r] * alpha[r] + s;
        }
#pragma unroll
        for (int nf = 0; nf < 8; ++nf)
#pragma unroll
          for (int r = 0; r < 4; ++r) o_acc[nf][r] *= alpha[r];

#pragma unroll
        for (int sf = 0; sf < 4; ++sf)
#pragma unroll
          for (int r = 0; r < 4; ++r) {
            int row = lg * 4 + r, col = sf * 16 + lr;
            int byteoff = (row * 128 + col * 2) ^ ((row & 7) << 4);
            *(u16*)((char*)Plds[w] + byteoff) = f2bf(p[sf][r]);
          }

#pragma unroll
        for (int ks = 0; ks < 2; ++ks) {
          bf16x8 pfrag = *(const bf16x8*)((char*)Plds[w] + ((lr * 128 + ks * 64 + lg * 16) ^ ((lr & 7) << 4)));
#pragma unroll
          for (int nf = 0; nf < 8; ++nf) {
            int vrow = nf * 16 + lr;
            int cc = ks * 4 + lg;
            bf16x8 vfrag = *(const bf16x8*)((char*)Vlds[cur] + vrow * 128 + ((cc ^ (vrow & 7)) << 4));
            o_acc[nf] = __builtin_amdgcn_mfma_f32_16x16x32_bf16(pfrag, vfrag, o_acc[nf], 0, 0, 0);
          }
        }
      }

      __syncthreads();
      cur ^= 1;
    }

    float inv[4];
#pragma unroll
    for (int r = 0; r < 4; ++r) inv[r] = 1.0f / lrow[r];
#pragma unroll
    for (int nf = 0; nf < 8; ++nf)
#pragma unroll
      for (int r = 0; r < 4; ++r) {
        int grow = qbase + w * 16 + lg * 4 + r;
        int col  = nf * 16 + lr;
        AO[(size_t)(b * SS + grow) * DIM + h * HD + col] = f2bf(o_acc[nf][r] * inv[r]);
      }
#undef STAGE
  }
}

// ---------------- launch ----------------
extern "C" void kernel_launch(void* const* d_in, const int* in_sizes, int n_in,
                              void* d_out, int out_size, void* d_ws, size_t ws_size,
                              hipStream_t stream)
{
  const float* x  = (const float*)d_in[0];
  const float* Wq = (const float*)d_in[1];
  const float* Wk = (const float*)d_in[2];
  const float* Wv = (const float*)d_in[3];
  const float* Wo = (const float*)d_in[4];
  float* out = (float*)d_out;

  char* ws = (char*)d_ws;
  const size_t XB_BYTES = (size_t)MTOT * DIM * 2;   // 16 MB
  const size_t W_BYTES  = (size_t)DIM * DIM * 2;    // 8 MB
  u16* xb = (u16*)ws;                                // x bf16; later reused as AO
  u16* w0 = (u16*)(ws + XB_BYTES);                   // Wq, later Wo
  u16* w1 = (u16*)(ws + XB_BYTES + W_BYTES);         // Wk, later VT (spans w1+w2)
  u16* w2 = (u16*)(ws + XB_BYTES + 2 * W_BYTES);     // Wv
  u16* Qb = (u16*)(ws + XB_BYTES + 3 * W_BYTES);
  u16* Kb = Qb + (size_t)MTOT * DIM;
  u16* Vb = Kb + (size_t)MTOT * DIM;
  u16* AO = xb;
  u16* VTb = w1;                                     // 16 MB (w1+w2), free after QKV GEMM

  cvt_all<<<20480, 256, 0, stream>>>(x, Wq, Wk, Wv, xb, w0, w1, w2);

  gemm256<true><<<dim3(384), 512, 0, stream>>>(xb, w0, w1, w2,
                                               (void*)Qb, (void*)Kb, (void*)Vb);

  transpose_v<<<dim3(32, 2, 32), 256, 0, stream>>>(Vb, VTb);

  rope_kernel<<<16384, 256, 0, stream>>>(Qb, Kb);

  cvt_kernel<<<4096, 256, 0, stream>>>(Wo, w0, 1048576);  // Wq slot no longer needed

  attn_kernel<<<dim3(8, 32), 512, 0, stream>>>(Qb, Kb, VTb, AO);

  gemm256<false><<<dim3(128), 512, 0, stream>>>(AO, w0, w0, w0,
                                                (void*)out, (void*)out, (void*)out);
}